// Round 1
// baseline (495.512 us; speedup 1.0000x reference)
//
#include <hip/hip_runtime.h>

// ============================================================================
// Fused rCM attention block: qkv-proj -> flash attention -> skip-fuse -> proj
// B=4, N=2048, C=1024, H=16, Dh=64.  All matmuls on bf16 MFMA (2% abs tol).
//
// ws layout (bytes):
//   [0,256)                 coeff: c_skip, c_out
//   +16.78MB  Xbf   bf16 x            [8192][1024]
//   +6.29MB   WqkvT bf16 Wqkv^T       [3072][1024]
//   +2.10MB   WprojT bf16 Wproj^T     [1024][1024]
//   +16.78MB  Qb    bf16 [B,H,N,Dh]
//   +16.78MB  Kb    bf16 [B,H,N,Dh]
//   +16.78MB  Vb    bf16 [B,H,N,Dh]
//   +16.78MB  Hb    bf16 [B,N,C]  (c_skip*x + c_out*o)
//   total ~92.3 MB
// ============================================================================

typedef unsigned short ushort_t;
typedef __bf16 bf16x8 __attribute__((ext_vector_type(8)));
typedef float f32x4 __attribute__((ext_vector_type(4)));

#define GAS __attribute__((address_space(1)))
#define LAS __attribute__((address_space(3)))

static __device__ __forceinline__ ushort_t f2bf(float f) {
  union { float f; unsigned int u; } v; v.f = f;
  unsigned int r = v.u + 0x7fffu + ((v.u >> 16) & 1u);  // RNE
  return (ushort_t)(r >> 16);
}

static __device__ __forceinline__ void async16(const void* g, void* l) {
  // 16B per lane, LDS dest = wave-uniform base + lane*16
  __builtin_amdgcn_global_load_lds((const GAS unsigned int*)g,
                                   (LAS unsigned int*)l, 16, 0, 0);
}

// ---------------------------------------------------------------- coeff ----
__global__ void coeff_kernel(const float* __restrict__ t, float* __restrict__ c) {
  if (threadIdx.x == 0) {
    float cs = 0.f, co = 0.f;
    for (int i = 0; i < 4; ++i) {
      float ti = t[i];
      float d = 1.f + ti * ti;        // sigma_data = 1
      cs += 1.f / d;
      co += ti / sqrtf(d);
    }
    c[0] = cs * 0.25f;
    c[1] = co * 0.25f;
  }
}

// ------------------------------------------------------- fp32 -> bf16 ------
__global__ void cvt_kernel(const float* __restrict__ in, ushort_t* __restrict__ out, int n) {
  int i = (blockIdx.x * 256 + threadIdx.x) * 4;
  if (i < n) {
    float4 v = *(const float4*)(in + i);
    ushort4 o = make_ushort4(f2bf(v.x), f2bf(v.y), f2bf(v.z), f2bf(v.w));
    *(ushort4*)(out + i) = o;
  }
}

// ------------------------------------------- transpose + convert (W^T) -----
// in [R][C] fp32 row-major -> out [C][R] bf16 row-major
__global__ void transpose_cvt_kernel(const float* __restrict__ in, ushort_t* __restrict__ out,
                                     int R, int C) {
  __shared__ float tile[32][33];
  int bc = blockIdx.x * 32, br = blockIdx.y * 32;
  int tx = threadIdx.x & 31, ty = threadIdx.x >> 5;  // 256 threads, ty 0..7
#pragma unroll
  for (int i = 0; i < 32; i += 8)
    tile[ty + i][tx] = in[(size_t)(br + ty + i) * C + bc + tx];
  __syncthreads();
#pragma unroll
  for (int i = 0; i < 32; i += 8)
    out[(size_t)(bc + ty + i) * R + br + tx] = f2bf(tile[tx][ty + i]);
}

// ---------------------------------------------------- 128x128 GEMM core ----
// C[m0:+128][n0:+128] += A[M][K] @ Bt[N][K]^T, bf16 inputs, fp32 acc.
// m97 structure: BK=32, global_load_lds width16, 4 waves as 2x2 of 64x64.
static __device__ __forceinline__ void gemm128_core(
    const ushort_t* __restrict__ A, const ushort_t* __restrict__ Bt, int K,
    int m0, int n0, ushort_t* As, ushort_t* Bs, f32x4 acc[4][4]) {
  const int tid = threadIdx.x;
  const int wave = tid >> 6, lane = tid & 63;
  const int wm = (wave >> 1) * 64, wn = (wave & 1) * 64;
  const int lr = lane & 15, quad = lane >> 4;
  for (int kb = 0; kb < K; kb += 32) {
#pragma unroll
    for (int i = 0; i < 2; ++i) {
      int c = (i * 4 + wave) * 64 + lane;   // 16B-chunk index 0..511
      int row = c >> 2, cg = (c & 3) * 8;   // 4 chunks per 32-elem row
      async16(A + (size_t)(m0 + row) * K + kb + cg, As + (i * 4 + wave) * 512);
      async16(Bt + (size_t)(n0 + row) * K + kb + cg, Bs + (i * 4 + wave) * 512);
    }
    __syncthreads();
    bf16x8 af[4], bfr[4];
#pragma unroll
    for (int i = 0; i < 4; ++i) {
      af[i]  = *(const bf16x8*)(As + (wm + i * 16 + lr) * 32 + quad * 8);
      bfr[i] = *(const bf16x8*)(Bs + (wn + i * 16 + lr) * 32 + quad * 8);
    }
#pragma unroll
    for (int i = 0; i < 4; ++i)
#pragma unroll
      for (int j = 0; j < 4; ++j)
        acc[i][j] = __builtin_amdgcn_mfma_f32_16x16x32_bf16(af[i], bfr[j], acc[i][j], 0, 0, 0);
    __syncthreads();
  }
}

// ------------------------------------------------------------ QKV GEMM -----
// X[8192][1024] @ Wqkv -> Q/K/V bf16 [B,H,N,Dh], bias fused.
__global__ __launch_bounds__(256) void gemm_qkv_kernel(
    const ushort_t* __restrict__ Xbf, const ushort_t* __restrict__ Wt,
    const float* __restrict__ bqkv, ushort_t* __restrict__ Qb,
    ushort_t* __restrict__ Kb, ushort_t* __restrict__ Vb) {
  __shared__ __align__(16) ushort_t As[128 * 32];
  __shared__ __align__(16) ushort_t Bs[128 * 32];
  const int m0 = (blockIdx.x & 63) << 7;   // 64 m-tiles
  const int n0 = (blockIdx.x >> 6) << 7;   // 24 n-tiles
  f32x4 acc[4][4];
#pragma unroll
  for (int i = 0; i < 4; ++i)
#pragma unroll
    for (int j = 0; j < 4; ++j) acc[i][j] = f32x4{0.f, 0.f, 0.f, 0.f};
  gemm128_core(Xbf, Wt, 1024, m0, n0, As, Bs, acc);

  const int tid = threadIdx.x, wave = tid >> 6, lane = tid & 63;
  const int wm = (wave >> 1) * 64, wn = (wave & 1) * 64;
  const int col = lane & 15, quad = lane >> 4;
  const int b = m0 >> 11;  // 16 m-tiles per batch -> uniform per block
#pragma unroll
  for (int j = 0; j < 4; ++j) {
    int jc = n0 + wn + j * 16 + col;
    float bj = bqkv[jc];
    int which = jc >> 10, rem = jc & 1023;
    int hh = rem >> 6, d = rem & 63;
    ushort_t* dst = which == 0 ? Qb : (which == 1 ? Kb : Vb);
    size_t base = ((size_t)(b * 16 + hh) * 2048) * 64 + d;
#pragma unroll
    for (int i = 0; i < 4; ++i) {
#pragma unroll
      for (int r = 0; r < 4; ++r) {
        int m = m0 + wm + i * 16 + quad * 4 + r;  // C-layout row
        int nseq = m & 2047;
        dst[base + (size_t)nseq * 64] = f2bf(acc[i][j][r] + bj);
      }
    }
  }
}

// ------------------------------------------------------------ Out GEMM -----
__global__ __launch_bounds__(256) void gemm_out_kernel(
    const ushort_t* __restrict__ Hbf, const ushort_t* __restrict__ Wt,
    const float* __restrict__ bproj, float* __restrict__ out) {
  __shared__ __align__(16) ushort_t As[128 * 32];
  __shared__ __align__(16) ushort_t Bs[128 * 32];
  const int m0 = (blockIdx.x & 63) << 7;
  const int n0 = (blockIdx.x >> 6) << 7;   // 8 n-tiles
  f32x4 acc[4][4];
#pragma unroll
  for (int i = 0; i < 4; ++i)
#pragma unroll
    for (int j = 0; j < 4; ++j) acc[i][j] = f32x4{0.f, 0.f, 0.f, 0.f};
  gemm128_core(Hbf, Wt, 1024, m0, n0, As, Bs, acc);

  const int tid = threadIdx.x, wave = tid >> 6, lane = tid & 63;
  const int wm = (wave >> 1) * 64, wn = (wave & 1) * 64;
  const int col = lane & 15, quad = lane >> 4;
#pragma unroll
  for (int j = 0; j < 4; ++j) {
    int jc = n0 + wn + j * 16 + col;
    float bj = bproj[jc];
#pragma unroll
    for (int i = 0; i < 4; ++i) {
#pragma unroll
      for (int r = 0; r < 4; ++r) {
        int m = m0 + wm + i * 16 + quad * 4 + r;
        out[(size_t)m * 1024 + jc] = acc[i][j][r] + bj;
      }
    }
  }
}

// ------------------------------------------------------ flash attention ----
// One block = 64 Q-rows of one (b,h). 4 waves x 16 rows. K/V tiles of 128.
// Epilogue fuses h = c_skip*x + c_out*(o/l) -> bf16 H.
__global__ __launch_bounds__(256) void attn_kernel(
    const ushort_t* __restrict__ Qb, const ushort_t* __restrict__ Kb,
    const ushort_t* __restrict__ Vb, const float* __restrict__ x,
    const float* __restrict__ coef, ushort_t* __restrict__ Hbf) {
  // Qs[64][72] | Ks[128][72] | Vs(d-major)[64][136]; Ps[64][136] aliases Ks
  __shared__ __align__(16) ushort_t smem[64 * 72 + 128 * 72 + 64 * 136];
  ushort_t* Qs = smem;
  ushort_t* Ks = smem + 64 * 72;
  ushort_t* Vs = smem + 64 * 72 + 128 * 72;
  ushort_t* Ps = Ks;  // 64*136=8704 <= 128*72=9216

  const int tid = threadIdx.x, wave = tid >> 6, lane = tid & 63;
  const int col = lane & 15, quad = lane >> 4;
  const int bh = blockIdx.x >> 5, qt = blockIdx.x & 31;

  const ushort_t* Qg = Qb + ((size_t)bh * 2048 + qt * 64) * 64;
  const ushort_t* Kg = Kb + (size_t)bh * 2048 * 64;
  const ushort_t* Vg = Vb + (size_t)bh * 2048 * 64;

  // stage Q tile [64][64] -> [64][72]
#pragma unroll
  for (int i = 0; i < 2; ++i) {
    int idx = (i * 256 + tid) * 8;
    int r = idx >> 6, c = idx & 63;
    *(uint4*)(Qs + r * 72 + c) = *(const uint4*)(Qg + idx);
  }

  float mst[4], lst[4], alpha[4];
  f32x4 oacc[4];
#pragma unroll
  for (int r = 0; r < 4; ++r) { mst[r] = -1e30f; lst[r] = 0.f; }
#pragma unroll
  for (int dt = 0; dt < 4; ++dt) oacc[dt] = f32x4{0.f, 0.f, 0.f, 0.f};

  for (int kt = 0; kt < 16; ++kt) {
    __syncthreads();  // B0: prior PV reads done before restaging Ks/Vs
    const ushort_t* Kgt = Kg + (size_t)kt * 128 * 64;
    const ushort_t* Vgt = Vg + (size_t)kt * 128 * 64;
#pragma unroll
    for (int i = 0; i < 4; ++i) {   // K tile [128][64] -> [128][72]
      int idx = (i * 256 + tid) * 8;
      int r = idx >> 6, c = idx & 63;
      *(uint4*)(Ks + r * 72 + c) = *(const uint4*)(Kgt + idx);
    }
#pragma unroll
    for (int i = 0; i < 4; ++i) {   // V tile transposed: Vs[d][n]
      int idx = (i * 256 + tid) * 8;
      int n = idx >> 6, d0 = idx & 63;
      ushort_t tmp[8];
      *(uint4*)tmp = *(const uint4*)(Vgt + idx);
#pragma unroll
      for (int j = 0; j < 8; ++j) Vs[(d0 + j) * 136 + n] = tmp[j];
    }
    __syncthreads();  // B1: staging visible

    // S = Q K^T * scale  (wave's 16 rows x 128 cols)
    bf16x8 qf0 = *(const bf16x8*)(Qs + (wave * 16 + col) * 72 + quad * 8);
    bf16x8 qf1 = *(const bf16x8*)(Qs + (wave * 16 + col) * 72 + 32 + quad * 8);
    f32x4 s[8];
#pragma unroll
    for (int nt = 0; nt < 8; ++nt) {
      bf16x8 kf0 = *(const bf16x8*)(Ks + (nt * 16 + col) * 72 + quad * 8);
      bf16x8 kf1 = *(const bf16x8*)(Ks + (nt * 16 + col) * 72 + 32 + quad * 8);
      f32x4 a = f32x4{0.f, 0.f, 0.f, 0.f};
      a = __builtin_amdgcn_mfma_f32_16x16x32_bf16(qf0, kf0, a, 0, 0, 0);
      a = __builtin_amdgcn_mfma_f32_16x16x32_bf16(qf1, kf1, a, 0, 0, 0);
      s[nt] = a * 0.125f;  // Dh^-0.5
    }

    // online softmax: rows quad*4+r, cols spread over 16 lanes x 8 tiles
#pragma unroll
    for (int r = 0; r < 4; ++r) {
      float v = s[0][r];
#pragma unroll
      for (int nt = 1; nt < 8; ++nt) v = fmaxf(v, s[nt][r]);
#pragma unroll
      for (int off = 1; off < 16; off <<= 1) v = fmaxf(v, __shfl_xor(v, off));
      float mn = fmaxf(mst[r], v);
      alpha[r] = __expf(mst[r] - mn);
      mst[r] = mn;
    }
    float rs[4] = {0.f, 0.f, 0.f, 0.f};
#pragma unroll
    for (int nt = 0; nt < 8; ++nt) {
#pragma unroll
      for (int r = 0; r < 4; ++r) {
        float p = __expf(s[nt][r] - mst[r]);
        s[nt][r] = p;
        rs[r] += p;
      }
    }
#pragma unroll
    for (int r = 0; r < 4; ++r) {
#pragma unroll
      for (int off = 1; off < 16; off <<= 1) rs[r] += __shfl_xor(rs[r], off);
      lst[r] = lst[r] * alpha[r] + rs[r];
    }
#pragma unroll
    for (int dt = 0; dt < 4; ++dt)
#pragma unroll
      for (int r = 0; r < 4; ++r) oacc[dt][r] *= alpha[r];

    __syncthreads();  // B2: all Ks reads done before P overwrites it
    // P: C-layout -> LDS [row][136] (bf16) for A-layout reads
#pragma unroll
    for (int nt = 0; nt < 8; ++nt)
#pragma unroll
      for (int r = 0; r < 4; ++r)
        Ps[(wave * 16 + quad * 4 + r) * 136 + nt * 16 + col] = f2bf(s[nt][r]);
    __syncthreads();  // B3

    // O += P @ V  (A-frag: rows = wave's own 16, k = n)
#pragma unroll
    for (int kk = 0; kk < 4; ++kk) {
      bf16x8 pf = *(const bf16x8*)(Ps + (wave * 16 + col) * 136 + kk * 32 + quad * 8);
#pragma unroll
      for (int dt = 0; dt < 4; ++dt) {
        bf16x8 vf = *(const bf16x8*)(Vs + (dt * 16 + col) * 136 + kk * 32 + quad * 8);
        oacc[dt] = __builtin_amdgcn_mfma_f32_16x16x32_bf16(pf, vf, oacc[dt], 0, 0, 0);
      }
    }
  }

  // epilogue: h = c_skip*x + c_out*(o/l) -> bf16
  const int b = bh >> 4, hh = bh & 15;
  float cs = coef[0], co = coef[1];
#pragma unroll
  for (int dt = 0; dt < 4; ++dt) {
#pragma unroll
    for (int r = 0; r < 4; ++r) {
      int row = wave * 16 + quad * 4 + r;
      int nseq = qt * 64 + row;
      int c = hh * 64 + dt * 16 + col;
      size_t midx = ((size_t)b * 2048 + nseq) * 1024 + c;
      float o = oacc[dt][r] / lst[r];
      Hbf[midx] = f2bf(cs * x[midx] + co * o);
    }
  }
}

// ============================================================================
extern "C" void kernel_launch(void* const* d_in, const int* in_sizes, int n_in,
                              void* d_out, int out_size, void* d_ws, size_t ws_size,
                              hipStream_t stream) {
  const float* x     = (const float*)d_in[0];
  const float* t     = (const float*)d_in[1];
  const float* Wqkv  = (const float*)d_in[2];
  const float* bqkv  = (const float*)d_in[3];
  const float* Wproj = (const float*)d_in[4];
  const float* bproj = (const float*)d_in[5];
  float* out = (float*)d_out;
  char* ws = (char*)d_ws;

  float* coef = (float*)ws;
  ushort_t* Xbf    = (ushort_t*)(ws + 256);
  ushort_t* WqkvT  = (ushort_t*)(ws + 256 + 16777216);
  ushort_t* WprojT = (ushort_t*)(ws + 256 + 16777216 + 6291456);
  ushort_t* Qb     = (ushort_t*)(ws + 256 + 16777216 + 6291456 + 2097152);
  ushort_t* Kb = Qb + 8388608;
  ushort_t* Vb = Kb + 8388608;
  ushort_t* Hb = Vb + 8388608;

  coeff_kernel<<<1, 64, 0, stream>>>(t, coef);
  cvt_kernel<<<8192, 256, 0, stream>>>(x, Xbf, 8388608);
  transpose_cvt_kernel<<<dim3(96, 32), 256, 0, stream>>>(Wqkv, WqkvT, 1024, 3072);
  transpose_cvt_kernel<<<dim3(32, 32), 256, 0, stream>>>(Wproj, WprojT, 1024, 1024);
  gemm_qkv_kernel<<<1536, 256, 0, stream>>>(Xbf, WqkvT, bqkv, Qb, Kb, Vb);
  attn_kernel<<<2048, 256, 0, stream>>>(Qb, Kb, Vb, x, coef, Hb);
  gemm_out_kernel<<<512, 256, 0, stream>>>(Hb, WprojT, bproj, out);
}